// Round 5
// baseline (801.665 us; speedup 1.0000x reference)
//
#include <hip/hip_runtime.h>

#define D 128

typedef __attribute__((ext_vector_type(8))) short bf16x8;
typedef __attribute__((ext_vector_type(4))) float f32x4;

__device__ __forceinline__ unsigned fenc(float f) {
    unsigned u = __float_as_uint(f);
    return (u & 0x80000000u) ? ~u : (u | 0x80000000u);
}
__device__ __forceinline__ float fdec(unsigned u) {
    return (u & 0x80000000u) ? __uint_as_float(u ^ 0x80000000u) : __uint_as_float(~u);
}
__device__ __forceinline__ unsigned short f2b(float f) {   // f32 -> bf16 (RNE)
    unsigned u = __float_as_uint(f);
    return (unsigned short)((u + 0x7fffu + ((u >> 16) & 1u)) >> 16);
}

// ---------------- input conversion f32 -> bf16 ----------------
__global__ void conv_bf16(const float* __restrict__ in, unsigned short* __restrict__ out,
                          int count8) {
    int t = blockIdx.x * blockDim.x + threadIdx.x;
    if (t >= count8) return;
    const float4* p = (const float4*)(in + (size_t)t * 8);
    float4 a = p[0], b = p[1];
    bf16x8 o;
    o[0] = (short)f2b(a.x); o[1] = (short)f2b(a.y);
    o[2] = (short)f2b(a.z); o[3] = (short)f2b(a.w);
    o[4] = (short)f2b(b.x); o[5] = (short)f2b(b.y);
    o[6] = (short)f2b(b.z); o[7] = (short)f2b(b.w);
    *(bf16x8*)(out + (size_t)t * 8) = o;
}

// pack W (f32 [K=128][N=128]) into per-(coltile,kstep,lane) B fragments, bf16
__global__ void pack_w(const float* __restrict__ W, unsigned short* __restrict__ Wp) {
    int idx = blockIdx.x * blockDim.x + threadIdx.x;
    if (idx >= 16384) return;
    int j  = idx & 7;
    int l  = (idx >> 3) & 63;
    int ks = (idx >> 9) & 3;
    int ct = idx >> 11;
    int k = ks * 32 + ((l >> 4) << 3) + j;
    int c = ct * 16 + (l & 15);
    Wp[idx] = f2b(W[(size_t)k * D + c]);
}

// ---------------- MFMA GEMM: h16 = bf16(x @ W), fused as_/ad_ dots ----------------
__global__ __launch_bounds__(256) void gemm_mfma(const unsigned short* __restrict__ xb,
                                                 const unsigned short* __restrict__ Wp,
                                                 const float* __restrict__ a_src,
                                                 const float* __restrict__ a_dst,
                                                 unsigned short* __restrict__ h16,
                                                 float* __restrict__ as_, float* __restrict__ ad_,
                                                 int n) {
    __shared__ float lds[4][16][132];
    int wv = threadIdx.x >> 6;
    int lane = threadIdx.x & 63;
    int base = blockIdx.x * 64 + wv * 16;
    int arow = base + (lane & 15);
    if (arow >= n) arow = n - 1;
    const bf16x8* aptr = (const bf16x8*)(xb + (size_t)arow * D + ((lane >> 4) << 3));
    const bf16x8* bp = (const bf16x8*)Wp;

    f32x4 acc[8];
#pragma unroll
    for (int ct = 0; ct < 8; ++ct) acc[ct] = (f32x4){0.f, 0.f, 0.f, 0.f};

#pragma unroll
    for (int ks = 0; ks < 4; ++ks) {
        bf16x8 af = aptr[ks * 4];
#pragma unroll
        for (int ct = 0; ct < 8; ++ct) {
            bf16x8 bf_ = bp[(ct * 4 + ks) * 64 + lane];
            acc[ct] = __builtin_amdgcn_mfma_f32_16x16x32_bf16(af, bf_, acc[ct], 0, 0, 0);
        }
    }

    int r0 = (lane >> 4) * 4;
    int c0 = lane & 15;
#pragma unroll
    for (int ct = 0; ct < 8; ++ct)
#pragma unroll
        for (int i = 0; i < 4; ++i)
            lds[wv][r0 + i][ct * 16 + c0] = acc[ct][i];
    __syncthreads();

#pragma unroll
    for (int i = 0; i < 4; ++i) {
        int r = (lane >> 4) + i * 4;
        int gr = base + r;
        if (gr < n) {
            const float* row = lds[wv][r];
            bf16x8 o;
#pragma unroll
            for (int j = 0; j < 8; ++j) o[j] = (short)f2b(row[c0 * 8 + j]);
            *(bf16x8*)(h16 + (size_t)gr * D + c0 * 8) = o;
        }
    }

    int r = lane >> 2, q = lane & 3;
    float s1 = 0.f, s2 = 0.f;
    const float* row = lds[wv][r];
#pragma unroll
    for (int c = 0; c < 32; ++c) {
        float hv = row[q * 32 + c];
        s1 = fmaf(hv, a_src[q * 32 + c], s1);
        s2 = fmaf(hv, a_dst[q * 32 + c], s2);
    }
    s1 += __shfl_xor(s1, 1); s1 += __shfl_xor(s1, 2);
    s2 += __shfl_xor(s2, 1); s2 += __shfl_xor(s2, 2);
    int gr = base + r;
    if (q == 0 && gr < n) { as_[gr] = s1; ad_[gr] = s2; }
}

// ---------------- CSR build (graph is layer-invariant) ----------------

__global__ void deg_hist(const int* __restrict__ ad_idx, int E, int n, int* __restrict__ cnt) {
    int e = blockIdx.x * blockDim.x + threadIdx.x;
    if (e >= E + n) return;
    int dst = (e < E) ? ad_idx[E + e] : (e - E);
    atomicAdd(&cnt[dst], 1);
}

__global__ void scan1(const int* __restrict__ cnt, int* __restrict__ start,
                      int* __restrict__ bsum, int n) {
    __shared__ int lds[256];
    int t = threadIdx.x;
    int i = blockIdx.x * 256 + t;
    int v = (i < n) ? cnt[i] : 0;
    lds[t] = v;
    __syncthreads();
    for (int off = 1; off < 256; off <<= 1) {
        int o = (t >= off) ? lds[t - off] : 0;
        __syncthreads();
        lds[t] += o;
        __syncthreads();
    }
    int incl = lds[t];
    if (i < n) start[i] = incl - v;
    if (t == 255) bsum[blockIdx.x] = incl;
}

__global__ void scan2(int* __restrict__ bsum, int nb) {
    __shared__ int lds[256];
    int t = threadIdx.x;
    int v = (t < nb) ? bsum[t] : 0;
    lds[t] = v;
    __syncthreads();
    for (int off = 1; off < 256; off <<= 1) {
        int o = (t >= off) ? lds[t - off] : 0;
        __syncthreads();
        lds[t] += o;
        __syncthreads();
    }
    if (t < nb) bsum[t] = lds[t] - v;
}

__global__ void scan3(int* __restrict__ start, const int* __restrict__ bsum, int n) {
    int i = blockIdx.x * blockDim.x + threadIdx.x;
    if (i < n) start[i] += bsum[blockIdx.x];
}

__global__ void csr_scatter(const int* __restrict__ ad_idx, int E, int n,
                            const int* __restrict__ start, int* __restrict__ cursor,
                            int* __restrict__ csr_src) {
    int e = blockIdx.x * blockDim.x + threadIdx.x;
    if (e >= E + n) return;
    int src, dst;
    if (e < E) { src = ad_idx[e]; dst = ad_idx[E + e]; }
    else       { src = dst = e - E; }
    int r = atomicAdd(&cursor[dst], 1);
    csr_src[start[dst] + r] = src;
}

// ------- fused per-node edge softmax + gather + bias + relu (+ L2 head fusion) -------
// one wave per node; quarter-waves process 4 edges in parallel, 8 dims/lane
__global__ void gat_aggregate(const int* __restrict__ csr_src, const int* __restrict__ start,
                              const int* __restrict__ deg, const float* __restrict__ as_,
                              const float* __restrict__ ad_, const unsigned short* __restrict__ h16,
                              const float* __restrict__ bias,
                              unsigned short* __restrict__ out16,        // L1 path
                              float* __restrict__ xout, float* __restrict__ sout,  // L2 path
                              const float* __restrict__ w_lin, const float* __restrict__ b_lin,
                              const int* __restrict__ resmask, float* __restrict__ pr,
                              unsigned* __restrict__ limax_u, const int* __restrict__ num_res,
                              int n) {
    int wid = threadIdx.x >> 6;
    int lane = threadIdx.x & 63;
    int node = blockIdx.x * 4 + wid;
    if (node >= n) return;
    int s0 = start[node];
    int dg = deg[node];
    float adv = ad_[node];
    int q = lane >> 4;        // edge slot within group of 4
    int dloc = lane & 15;     // dim block: dims dloc*8 .. dloc*8+7

    float acc[8];
#pragma unroll
    for (int t = 0; t < 8; ++t) acc[t] = 0.f;
    bool fast = (dg <= 64);

    if (fast) {
        bool ok = lane < dg;
        int sj = ok ? csr_src[s0 + lane] : 0;
        float v = -3.4e38f;
        if (ok) {
            v = as_[sj] + adv;
            v = v >= 0.f ? v : 0.2f * v;
        }
        float m = v;
        for (int off = 32; off; off >>= 1) m = fmaxf(m, __shfl_xor(m, off));
        float e = ok ? __expf(v - m) : 0.f;
        float ds = e;
        for (int off = 32; off; off >>= 1) ds += __shfl_xor(ds, off);
        float al = e / (ds + 1e-16f);

        for (int i = 0; i < dg; i += 4) {
            int j = i + q;                       // dg<=64 -> i<=60 -> j<=63
            float a = __shfl(al, j);             // j>=dg lanes carry al=0
            int   s = __shfl(sj, j);
            bf16x8 hv = *(const bf16x8*)(h16 + (size_t)s * D + dloc * 8);
            const unsigned* hu = (const unsigned*)&hv;
#pragma unroll
            for (int t2 = 0; t2 < 4; ++t2) {
                unsigned u = hu[t2];
                acc[2 * t2]     = fmaf(a, __uint_as_float(u << 16), acc[2 * t2]);
                acc[2 * t2 + 1] = fmaf(a, __uint_as_float(u & 0xffff0000u), acc[2 * t2 + 1]);
            }
        }
        // combine quarter-wave partials (same dloc at lane^16, lane^32, lane^48)
#pragma unroll
        for (int t = 0; t < 8; ++t) {
            acc[t] += __shfl_xor(acc[t], 16);
            acc[t] += __shfl_xor(acc[t], 32);
        }
    } else {
        // wave-uniform serial fallback (deg > 64); every lane builds full sums
        float m = -3.4e38f;
        for (int j = 0; j < dg; ++j) {
            float v = as_[csr_src[s0 + j]] + adv;
            v = v >= 0.f ? v : 0.2f * v;
            m = fmaxf(m, v);
        }
        float ds = 0.f;
        for (int j = 0; j < dg; ++j) {
            float v = as_[csr_src[s0 + j]] + adv;
            v = v >= 0.f ? v : 0.2f * v;
            ds += __expf(v - m);
        }
        float inv = 1.f / (ds + 1e-16f);
        for (int j = 0; j < dg; ++j) {
            int s = csr_src[s0 + j];
            float v = as_[s] + adv;
            v = v >= 0.f ? v : 0.2f * v;
            float a = __expf(v - m) * inv;
            bf16x8 hv = *(const bf16x8*)(h16 + (size_t)s * D + dloc * 8);
            const unsigned* hu = (const unsigned*)&hv;
#pragma unroll
            for (int t2 = 0; t2 < 4; ++t2) {
                unsigned u = hu[t2];
                acc[2 * t2]     = fmaf(a, __uint_as_float(u << 16), acc[2 * t2]);
                acc[2 * t2 + 1] = fmaf(a, __uint_as_float(u & 0xffff0000u), acc[2 * t2 + 1]);
            }
        }
    }

    // bias + relu (all lanes hold full sums for their dloc dims now)
    float4 b0 = *(const float4*)(bias + dloc * 8);
    float4 b1 = *(const float4*)(bias + dloc * 8 + 4);
    float o[8];
    o[0] = acc[0] + b0.x; o[1] = acc[1] + b0.y; o[2] = acc[2] + b0.z; o[3] = acc[3] + b0.w;
    o[4] = acc[4] + b1.x; o[5] = acc[5] + b1.y; o[6] = acc[6] + b1.z; o[7] = acc[7] + b1.w;
#pragma unroll
    for (int t = 0; t < 8; ++t) o[t] = o[t] > 0.f ? o[t] : 0.f;

    if (out16) {                                  // layer 1: bf16 for next GEMM
        if (q == 0) {
            bf16x8 o8;
#pragma unroll
            for (int t = 0; t < 8; ++t) o8[t] = (short)f2b(o[t]);
            *(bf16x8*)(out16 + (size_t)node * D + dloc * 8) = o8;
        }
    } else {                                      // layer 2: f32 out + fused head li
        if (q == 0) {
            float* xo = xout + (size_t)node * D + dloc * 8;
            *(float4*)xo       = make_float4(o[0], o[1], o[2], o[3]);
            *(float4*)(xo + 4) = make_float4(o[4], o[5], o[6], o[7]);
            if (node < num_res[0]) {
                float* so = sout + (size_t)node * D + dloc * 8;
                *(float4*)so       = make_float4(o[0], o[1], o[2], o[3]);
                *(float4*)(so + 4) = make_float4(o[4], o[5], o[6], o[7]);
            }
        }
        float4 w0 = *(const float4*)(w_lin + dloc * 8);
        float4 w1 = *(const float4*)(w_lin + dloc * 8 + 4);
        float part = o[0] * w0.x + o[1] * w0.y + o[2] * w0.z + o[3] * w0.w +
                     o[4] * w1.x + o[5] * w1.y + o[6] * w1.z + o[7] * w1.w;
        part += __shfl_xor(part, 1);
        part += __shfl_xor(part, 2);
        part += __shfl_xor(part, 4);
        part += __shfl_xor(part, 8);
        if (lane == 0) {
            float s = part + b_lin[0];
            if (resmask[node] == 0) s = -1000000000.0f;
            pr[node] = s;
            atomicMax(limax_u, fenc(s));
        }
    }
}

// ---------------- head ----------------

__global__ void head_exp(float* __restrict__ pr, const unsigned* __restrict__ limax_u,
                         float* __restrict__ sumexp, const int* __restrict__ resmask,
                         float* __restrict__ maskf, int n) {
    int i = blockIdx.x * blockDim.x + threadIdx.x;
    float m = fdec(*limax_u);
    float u = 0.f;
    if (i < n) {
        u = expf(pr[i] - m);
        pr[i] = u;
        maskf[i] = (float)resmask[i];
    }
    float t = u;
    for (int off = 32; off; off >>= 1) t += __shfl_down(t, off);
    if ((threadIdx.x & 63) == 0) atomicAdd(sumexp, t);
}

__global__ void head_final(float* __restrict__ pr, const float* __restrict__ sumexp,
                           const float* __restrict__ res, float* __restrict__ loss_out, int n) {
    int i = blockIdx.x * blockDim.x + threadIdx.x;
    float lt = 0.f;
    if (i < n) {
        float p = pr[i] / (*sumexp);
        pr[i] = p;
        float pc = fminf(fmaxf(p, 1e-10f), 1.0f);
        lt = -logf(pc) * res[i];
    }
    float t = lt;
    for (int off = 32; off; off >>= 1) t += __shfl_down(t, off);
    if ((threadIdx.x & 63) == 0) atomicAdd(loss_out, t);
}

extern "C" void kernel_launch(void* const* d_in, const int* in_sizes, int n_in,
                              void* d_out, int out_size, void* d_ws, size_t ws_size,
                              hipStream_t stream) {
    const float* input_node = (const float*)d_in[0];
    const int*   inputad    = (const int*)d_in[1];
    const float* res        = (const float*)d_in[2];
    const int*   resmask    = (const int*)d_in[3];
    const int*   num_res    = (const int*)d_in[4];
    const float* W1     = (const float*)d_in[5];
    const float* a_src1 = (const float*)d_in[6];
    const float* a_dst1 = (const float*)d_in[7];
    const float* b1     = (const float*)d_in[8];
    const float* W2     = (const float*)d_in[9];
    const float* a_src2 = (const float*)d_in[10];
    const float* a_dst2 = (const float*)d_in[11];
    const float* b2     = (const float*)d_in[12];
    const float* w_lin  = (const float*)d_in[13];
    const float* b_lin  = (const float*)d_in[14];

    int n = in_sizes[0] / D;
    int E = in_sizes[1] / 2;
    int Et = E + n;

    // workspace carve (16B aligned pieces)
    char* w = (char*)d_ws;
    unsigned short* xb16 = (unsigned short*)w; w += (size_t)n * D * 2;
    unsigned short* h16  = (unsigned short*)w; w += (size_t)n * D * 2;
    unsigned short* Wp1 = (unsigned short*)w; w += 16384 * 2;
    unsigned short* Wp2 = (unsigned short*)w; w += 16384 * 2;
    float* as_   = (float*)w; w += (size_t)n * 4;
    float* ad_   = (float*)w; w += (size_t)n * 4;
    int*   deg   = (int*)w;   w += (size_t)n * 4;
    int*   startv= (int*)w;   w += (size_t)n * 4;
    int*   cursor= (int*)w;   w += (size_t)n * 4;
    int*   csr_src=(int*)w;   w += (size_t)Et * 4;
    int*   bsum  = (int*)w;   w += 1024;
    unsigned* limax_u = (unsigned*)w; w += 16;
    float* sumexp = (float*)w; w += 16;

    // d_out carve
    float* out0  = (float*)d_out;            // loss (1)
    float* prob  = out0 + 1;                 // N
    float* xout  = prob + n;                 // N*D
    float* maskf = xout + (size_t)n * D;     // N
    float* sout  = maskf + n;                // K*D

    dim3 blk(256);
    auto cdiv = [](long long a, long long b) { return (unsigned)((a + b - 1) / b); };
    unsigned nb = cdiv(n, 256);

    // scalar zero-inits up front
    hipMemsetAsync(limax_u, 0, 4, stream);
    hipMemsetAsync(sumexp, 0, 4, stream);
    hipMemsetAsync(out0, 0, 4, stream);
    hipMemsetAsync(deg, 0, (size_t)n * 4, stream);
    hipMemsetAsync(cursor, 0, (size_t)n * 4, stream);

    // ---- conversions / packing ----
    conv_bf16<<<cdiv((long long)n * D / 8, 256), blk, 0, stream>>>(input_node, xb16, n * D / 8);
    pack_w<<<64, blk, 0, stream>>>(W1, Wp1);
    pack_w<<<64, blk, 0, stream>>>(W2, Wp2);

    // ---- CSR build (once; graph shared by both layers) ----
    deg_hist<<<cdiv(Et, 256), blk, 0, stream>>>(inputad, E, n, deg);
    scan1<<<nb, blk, 0, stream>>>(deg, startv, bsum, n);
    scan2<<<1, blk, 0, stream>>>(bsum, (int)nb);
    scan3<<<nb, blk, 0, stream>>>(startv, bsum, n);
    csr_scatter<<<cdiv(Et, 256), blk, 0, stream>>>(inputad, E, n, startv, cursor, csr_src);

    unsigned agg_grid = cdiv(n, 4);
    unsigned gemm_grid = cdiv(n, 64);

    // ---- Layer 1 ----
    gemm_mfma<<<gemm_grid, blk, 0, stream>>>(xb16, Wp1, a_src1, a_dst1, h16, as_, ad_, n);
    gat_aggregate<<<agg_grid, blk, 0, stream>>>(csr_src, startv, deg, as_, ad_, h16, b1,
                                                xb16, nullptr, nullptr, nullptr, nullptr,
                                                nullptr, nullptr, nullptr, nullptr, n);

    // ---- Layer 2 (writes straight into d_out; fused head li) ----
    gemm_mfma<<<gemm_grid, blk, 0, stream>>>(xb16, Wp2, a_src2, a_dst2, h16, as_, ad_, n);
    gat_aggregate<<<agg_grid, blk, 0, stream>>>(csr_src, startv, deg, as_, ad_, h16, b2,
                                                nullptr, xout, sout, w_lin, b_lin,
                                                resmask, prob, limax_u, num_res, n);

    // ---- Head ----
    head_exp<<<cdiv(n, 256), blk, 0, stream>>>(prob, limax_u, sumexp, resmask, maskf, n);
    head_final<<<cdiv(n, 256), blk, 0, stream>>>(prob, sumexp, res, out0, n);
}

// Round 6
// 330.452 us; speedup vs baseline: 2.4260x; 2.4260x over previous
//
#include <hip/hip_runtime.h>

#define D 128
#define CACHE 8   // per-lane cached edges -> supports deg <= 512 (actual max ~45)

typedef __attribute__((ext_vector_type(8))) short bf16x8;
typedef __attribute__((ext_vector_type(4))) float f32x4;

__device__ __forceinline__ unsigned fenc(float f) {
    unsigned u = __float_as_uint(f);
    return (u & 0x80000000u) ? ~u : (u | 0x80000000u);
}
__device__ __forceinline__ float fdec(unsigned u) {
    return (u & 0x80000000u) ? __uint_as_float(u ^ 0x80000000u) : __uint_as_float(~u);
}
__device__ __forceinline__ unsigned short f2b(float f) {   // f32 -> bf16 (RNE)
    unsigned u = __float_as_uint(f);
    return (unsigned short)((u + 0x7fffu + ((u >> 16) & 1u)) >> 16);
}

// ---------------- input conversion f32 -> bf16 ----------------
__global__ void conv_bf16(const float* __restrict__ in, unsigned short* __restrict__ out,
                          int count8) {
    int t = blockIdx.x * blockDim.x + threadIdx.x;
    if (t >= count8) return;
    const float4* p = (const float4*)(in + (size_t)t * 8);
    float4 a = p[0], b = p[1];
    bf16x8 o;
    o[0] = (short)f2b(a.x); o[1] = (short)f2b(a.y);
    o[2] = (short)f2b(a.z); o[3] = (short)f2b(a.w);
    o[4] = (short)f2b(b.x); o[5] = (short)f2b(b.y);
    o[6] = (short)f2b(b.z); o[7] = (short)f2b(b.w);
    *(bf16x8*)(out + (size_t)t * 8) = o;
}

// pack W (f32 [K=128][N=128]) into per-(coltile,kstep,lane) B fragments, bf16
__global__ void pack_w(const float* __restrict__ W, unsigned short* __restrict__ Wp) {
    int idx = blockIdx.x * blockDim.x + threadIdx.x;
    if (idx >= 16384) return;
    int j  = idx & 7;
    int l  = (idx >> 3) & 63;
    int ks = (idx >> 9) & 3;
    int ct = idx >> 11;
    int k = ks * 32 + ((l >> 4) << 3) + j;
    int c = ct * 16 + (l & 15);
    Wp[idx] = f2b(W[(size_t)k * D + c]);
}

// ---------------- MFMA GEMM: h16 = bf16(x @ W), fused as_/ad_ dots ----------------
__global__ __launch_bounds__(256) void gemm_mfma(const unsigned short* __restrict__ xb,
                                                 const unsigned short* __restrict__ Wp,
                                                 const float* __restrict__ a_src,
                                                 const float* __restrict__ a_dst,
                                                 unsigned short* __restrict__ h16,
                                                 float* __restrict__ as_, float* __restrict__ ad_,
                                                 int n) {
    __shared__ float lds[4][16][132];
    int wv = threadIdx.x >> 6;
    int lane = threadIdx.x & 63;
    int base = blockIdx.x * 64 + wv * 16;
    int arow = base + (lane & 15);
    if (arow >= n) arow = n - 1;
    const bf16x8* aptr = (const bf16x8*)(xb + (size_t)arow * D + ((lane >> 4) << 3));
    const bf16x8* bp = (const bf16x8*)Wp;

    f32x4 acc[8];
#pragma unroll
    for (int ct = 0; ct < 8; ++ct) acc[ct] = (f32x4){0.f, 0.f, 0.f, 0.f};

#pragma unroll
    for (int ks = 0; ks < 4; ++ks) {
        bf16x8 af = aptr[ks * 4];
#pragma unroll
        for (int ct = 0; ct < 8; ++ct) {
            bf16x8 bf_ = bp[(ct * 4 + ks) * 64 + lane];
            acc[ct] = __builtin_amdgcn_mfma_f32_16x16x32_bf16(af, bf_, acc[ct], 0, 0, 0);
        }
    }

    int r0 = (lane >> 4) * 4;
    int c0 = lane & 15;
#pragma unroll
    for (int ct = 0; ct < 8; ++ct)
#pragma unroll
        for (int i = 0; i < 4; ++i)
            lds[wv][r0 + i][ct * 16 + c0] = acc[ct][i];
    __syncthreads();

#pragma unroll
    for (int i = 0; i < 4; ++i) {
        int r = (lane >> 4) + i * 4;
        int gr = base + r;
        if (gr < n) {
            const float* row = lds[wv][r];
            bf16x8 o;
#pragma unroll
            for (int j = 0; j < 8; ++j) o[j] = (short)f2b(row[c0 * 8 + j]);
            *(bf16x8*)(h16 + (size_t)gr * D + c0 * 8) = o;
        }
    }

    int r = lane >> 2, q = lane & 3;
    float s1 = 0.f, s2 = 0.f;
    const float* row = lds[wv][r];
#pragma unroll
    for (int c = 0; c < 32; ++c) {
        float hv = row[q * 32 + c];
        s1 = fmaf(hv, a_src[q * 32 + c], s1);
        s2 = fmaf(hv, a_dst[q * 32 + c], s2);
    }
    s1 += __shfl_xor(s1, 1); s1 += __shfl_xor(s1, 2);
    s2 += __shfl_xor(s2, 1); s2 += __shfl_xor(s2, 2);
    int gr = base + r;
    if (q == 0 && gr < n) { as_[gr] = s1; ad_[gr] = s2; }
}

// ---------------- CSR build (graph is layer-invariant) ----------------

__global__ void deg_hist(const int* __restrict__ ad_idx, int E, int n, int* __restrict__ cnt) {
    int e = blockIdx.x * blockDim.x + threadIdx.x;
    if (e >= E + n) return;
    int dst = (e < E) ? ad_idx[E + e] : (e - E);
    atomicAdd(&cnt[dst], 1);
}

__global__ void scan1(const int* __restrict__ cnt, int* __restrict__ start,
                      int* __restrict__ bsum, int n) {
    __shared__ int lds[256];
    int t = threadIdx.x;
    int i = blockIdx.x * 256 + t;
    int v = (i < n) ? cnt[i] : 0;
    lds[t] = v;
    __syncthreads();
    for (int off = 1; off < 256; off <<= 1) {
        int o = (t >= off) ? lds[t - off] : 0;
        __syncthreads();
        lds[t] += o;
        __syncthreads();
    }
    int incl = lds[t];
    if (i < n) start[i] = incl - v;
    if (t == 255) bsum[blockIdx.x] = incl;
}

__global__ void scan2(int* __restrict__ bsum, int nb) {
    __shared__ int lds[256];
    int t = threadIdx.x;
    int v = (t < nb) ? bsum[t] : 0;
    lds[t] = v;
    __syncthreads();
    for (int off = 1; off < 256; off <<= 1) {
        int o = (t >= off) ? lds[t - off] : 0;
        __syncthreads();
        lds[t] += o;
        __syncthreads();
    }
    if (t < nb) bsum[t] = lds[t] - v;
}

__global__ void scan3(int* __restrict__ start, const int* __restrict__ bsum, int n) {
    int i = blockIdx.x * blockDim.x + threadIdx.x;
    if (i < n) start[i] += bsum[blockIdx.x];
}

__global__ void csr_scatter(const int* __restrict__ ad_idx, int E, int n,
                            const int* __restrict__ start, int* __restrict__ cursor,
                            int* __restrict__ csr_src) {
    int e = blockIdx.x * blockDim.x + threadIdx.x;
    if (e >= E + n) return;
    int src, dst;
    if (e < E) { src = ad_idx[e]; dst = ad_idx[E + e]; }
    else       { src = dst = e - E; }
    int r = atomicAdd(&cursor[dst], 1);
    csr_src[start[dst] + r] = src;
}

// ------- fused per-node edge softmax + gather + bias + relu (+ L2 head-li fusion) -------
// one wave per node; round-4 proven inner loop: uniform readlane gather,
// coalesced 4B/lane row reads (do NOT re-introduce the quarter-wave gather — R5 regression)
__global__ void gat_aggregate(const int* __restrict__ csr_src, const int* __restrict__ start,
                              const int* __restrict__ deg, const float* __restrict__ as_,
                              const float* __restrict__ ad_, const unsigned short* __restrict__ h16,
                              const float* __restrict__ bias,
                              unsigned short* __restrict__ out16,                   // L1 path
                              float* __restrict__ xout, float* __restrict__ sout,   // L2 path
                              const float* __restrict__ w_lin, const float* __restrict__ b_lin,
                              const int* __restrict__ resmask, float* __restrict__ pr,
                              const int* __restrict__ num_res, int n) {
    int wid = threadIdx.x >> 6;
    int lane = threadIdx.x & 63;
    int node = blockIdx.x * 4 + wid;
    if (node >= n) return;
    int s0 = start[node];
    int dg = deg[node];
    float adv = ad_[node];

    float vreg[CACHE];
    int   sreg[CACHE];
    float m = -3.4e38f;
#pragma unroll
    for (int c = 0; c < CACHE; ++c) {
        int j = c * 64 + lane;
        bool ok = j < dg;
        int s = ok ? csr_src[s0 + j] : 0;
        sreg[c] = s;
        float v = -3.4e38f;
        if (ok) {
            v = as_[s] + adv;
            v = v >= 0.f ? v : 0.2f * v;
        }
        vreg[c] = v;
        m = fmaxf(m, v);
    }
    for (int off = 32; off; off >>= 1) m = fmaxf(m, __shfl_xor(m, off));

    float dsum = 0.f;
#pragma unroll
    for (int c = 0; c < CACHE; ++c) {
        int j = c * 64 + lane;
        float e = (j < dg) ? __expf(vreg[c] - m) : 0.f;
        vreg[c] = e;
        dsum += e;
    }
    for (int off = 32; off; off >>= 1) dsum += __shfl_xor(dsum, off);
    float inv = 1.f / (dsum + 1e-16f);

    float acc0 = 0.f, acc1 = 0.f;
#pragma unroll
    for (int c = 0; c < CACHE; ++c) {
        if (c * 64 < dg) {
            int mc = min(64, dg - c * 64);
            for (int l = 0; l < mc; ++l) {
                float a   = __shfl(vreg[c], l) * inv;   // l uniform -> readlane
                int  srcj = __shfl(sreg[c], l);          // uniform row address
                unsigned hv = *(const unsigned*)(h16 + (size_t)srcj * D + lane * 2);
                acc0 = fmaf(a, __uint_as_float(hv << 16), acc0);
                acc1 = fmaf(a, __uint_as_float(hv & 0xffff0000u), acc1);
            }
        }
    }
    float2 bv = *(const float2*)(bias + lane * 2);
    float o0 = acc0 + bv.x, o1 = acc1 + bv.y;
    o0 = o0 > 0.f ? o0 : 0.f;
    o1 = o1 > 0.f ? o1 : 0.f;

    if (out16) {                                   // layer 1: bf16 for next GEMM
        ushort2 u2;
        u2.x = f2b(o0);
        u2.y = f2b(o1);
        *(ushort2*)(out16 + (size_t)node * D + lane * 2) = u2;
    } else {                                       // layer 2: d_out writes + fused head li
        *(float2*)(xout + (size_t)node * D + lane * 2) = make_float2(o0, o1);
        if (node < num_res[0])
            *(float2*)(sout + (size_t)node * D + lane * 2) = make_float2(o0, o1);
        float2 wv = *(const float2*)(w_lin + lane * 2);
        float part = fmaf(o0, wv.x, o1 * wv.y);
        for (int off = 32; off; off >>= 1) part += __shfl_xor(part, off);
        if (lane == 0) {
            float s = part + b_lin[0];
            if (resmask[node] == 0) s = -1000000000.0f;
            pr[node] = s;                          // no atomic here (50k-wave contention)
        }
    }
}

// ---------------- head ----------------

__global__ void head_max(const float* __restrict__ pr, unsigned* __restrict__ limax_u, int n) {
    unsigned mx = 0u;
    for (int i = blockIdx.x * blockDim.x + threadIdx.x; i < n; i += gridDim.x * blockDim.x) {
        unsigned e = fenc(pr[i]);
        mx = mx > e ? mx : e;
    }
    for (int off = 32; off; off >>= 1) {
        unsigned o = __shfl_xor(mx, off);
        mx = mx > o ? mx : o;
    }
    if ((threadIdx.x & 63) == 0) atomicMax(limax_u, mx);
}

__global__ void head_exp(float* __restrict__ pr, const unsigned* __restrict__ limax_u,
                         float* __restrict__ sumexp, const int* __restrict__ resmask,
                         float* __restrict__ maskf, int n) {
    int i = blockIdx.x * blockDim.x + threadIdx.x;
    float m = fdec(*limax_u);
    float u = 0.f;
    if (i < n) {
        u = expf(pr[i] - m);
        pr[i] = u;
        maskf[i] = (float)resmask[i];
    }
    float t = u;
    for (int off = 32; off; off >>= 1) t += __shfl_down(t, off);
    if ((threadIdx.x & 63) == 0) atomicAdd(sumexp, t);
}

__global__ void head_final(float* __restrict__ pr, const float* __restrict__ sumexp,
                           const float* __restrict__ res, float* __restrict__ loss_out, int n) {
    int i = blockIdx.x * blockDim.x + threadIdx.x;
    float lt = 0.f;
    if (i < n) {
        float p = pr[i] / (*sumexp);
        pr[i] = p;
        float pc = fminf(fmaxf(p, 1e-10f), 1.0f);
        lt = -logf(pc) * res[i];
    }
    float t = lt;
    for (int off = 32; off; off >>= 1) t += __shfl_down(t, off);
    if ((threadIdx.x & 63) == 0) atomicAdd(loss_out, t);
}

extern "C" void kernel_launch(void* const* d_in, const int* in_sizes, int n_in,
                              void* d_out, int out_size, void* d_ws, size_t ws_size,
                              hipStream_t stream) {
    const float* input_node = (const float*)d_in[0];
    const int*   inputad    = (const int*)d_in[1];
    const float* res        = (const float*)d_in[2];
    const int*   resmask    = (const int*)d_in[3];
    const int*   num_res    = (const int*)d_in[4];
    const float* W1     = (const float*)d_in[5];
    const float* a_src1 = (const float*)d_in[6];
    const float* a_dst1 = (const float*)d_in[7];
    const float* b1     = (const float*)d_in[8];
    const float* W2     = (const float*)d_in[9];
    const float* a_src2 = (const float*)d_in[10];
    const float* a_dst2 = (const float*)d_in[11];
    const float* b2     = (const float*)d_in[12];
    const float* w_lin  = (const float*)d_in[13];
    const float* b_lin  = (const float*)d_in[14];

    int n = in_sizes[0] / D;
    int E = in_sizes[1] / 2;
    int Et = E + n;

    // workspace carve (16B aligned pieces)
    char* w = (char*)d_ws;
    unsigned short* xb16 = (unsigned short*)w; w += (size_t)n * D * 2;
    unsigned short* h16  = (unsigned short*)w; w += (size_t)n * D * 2;
    unsigned short* Wp1 = (unsigned short*)w; w += 16384 * 2;
    unsigned short* Wp2 = (unsigned short*)w; w += 16384 * 2;
    float* as_   = (float*)w; w += (size_t)n * 4;
    float* ad_   = (float*)w; w += (size_t)n * 4;
    int*   deg   = (int*)w;   w += (size_t)n * 4;
    int*   startv= (int*)w;   w += (size_t)n * 4;
    int*   cursor= (int*)w;   w += (size_t)n * 4;
    int*   csr_src=(int*)w;   w += (size_t)Et * 4;
    int*   bsum  = (int*)w;   w += 1024;
    unsigned* limax_u = (unsigned*)w; w += 16;
    float* sumexp = (float*)w; w += 16;

    // d_out carve
    float* out0  = (float*)d_out;            // loss (1)
    float* prob  = out0 + 1;                 // N
    float* xout  = prob + n;                 // N*D
    float* maskf = xout + (size_t)n * D;     // N
    float* sout  = maskf + n;                // K*D

    dim3 blk(256);
    auto cdiv = [](long long a, long long b) { return (unsigned)((a + b - 1) / b); };
    unsigned nb = cdiv(n, 256);

    // scalar zero-inits up front
    hipMemsetAsync(limax_u, 0, 4, stream);
    hipMemsetAsync(sumexp, 0, 4, stream);
    hipMemsetAsync(out0, 0, 4, stream);
    hipMemsetAsync(deg, 0, (size_t)n * 4, stream);
    hipMemsetAsync(cursor, 0, (size_t)n * 4, stream);

    // ---- conversions / packing ----
    conv_bf16<<<cdiv((long long)n * D / 8, 256), blk, 0, stream>>>(input_node, xb16, n * D / 8);
    pack_w<<<64, blk, 0, stream>>>(W1, Wp1);
    pack_w<<<64, blk, 0, stream>>>(W2, Wp2);

    // ---- CSR build (once; graph shared by both layers) ----
    deg_hist<<<cdiv(Et, 256), blk, 0, stream>>>(inputad, E, n, deg);
    scan1<<<nb, blk, 0, stream>>>(deg, startv, bsum, n);
    scan2<<<1, blk, 0, stream>>>(bsum, (int)nb);
    scan3<<<nb, blk, 0, stream>>>(startv, bsum, n);
    csr_scatter<<<cdiv(Et, 256), blk, 0, stream>>>(inputad, E, n, startv, cursor, csr_src);

    unsigned agg_grid = cdiv(n, 4);
    unsigned gemm_grid = cdiv(n, 64);

    // ---- Layer 1 ----
    gemm_mfma<<<gemm_grid, blk, 0, stream>>>(xb16, Wp1, a_src1, a_dst1, h16, as_, ad_, n);
    gat_aggregate<<<agg_grid, blk, 0, stream>>>(csr_src, startv, deg, as_, ad_, h16, b1,
                                                xb16, nullptr, nullptr, nullptr, nullptr,
                                                nullptr, nullptr, nullptr, n);

    // ---- Layer 2 (writes straight into d_out; fused head li) ----
    gemm_mfma<<<gemm_grid, blk, 0, stream>>>(xb16, Wp2, a_src2, a_dst2, h16, as_, ad_, n);
    gat_aggregate<<<agg_grid, blk, 0, stream>>>(csr_src, startv, deg, as_, ad_, h16, b2,
                                                nullptr, xout, sout, w_lin, b_lin,
                                                resmask, prob, num_res, n);

    // ---- Head ----
    head_max<<<196, blk, 0, stream>>>(prob, limax_u, n);
    head_exp<<<nb, blk, 0, stream>>>(prob, limax_u, sumexp, resmask, maskf, n);
    head_final<<<nb, blk, 0, stream>>>(prob, sumexp, res, out0, n);
}

// Round 7
// 267.985 us; speedup vs baseline: 2.9915x; 1.2331x over previous
//
#include <hip/hip_runtime.h>

#define D 128
#define CACHE 8   // fallback path only (deg > 64; actual max deg ~45)

typedef __attribute__((ext_vector_type(8))) short bf16x8;
typedef __attribute__((ext_vector_type(4))) float f32x4;

__device__ __forceinline__ unsigned fenc(float f) {
    unsigned u = __float_as_uint(f);
    return (u & 0x80000000u) ? ~u : (u | 0x80000000u);
}
__device__ __forceinline__ float fdec(unsigned u) {
    return (u & 0x80000000u) ? __uint_as_float(u ^ 0x80000000u) : __uint_as_float(~u);
}
__device__ __forceinline__ unsigned short f2b(float f) {   // f32 -> bf16 (RNE)
    unsigned u = __float_as_uint(f);
    return (unsigned short)((u + 0x7fffu + ((u >> 16) & 1u)) >> 16);
}

// ---------------- fused conv_bf16 + pack_w1 + pack_w2 ----------------
__device__ __forceinline__ void pack_body(const float* __restrict__ W,
                                          unsigned short* __restrict__ Wp, int idx) {
    int j  = idx & 7;
    int l  = (idx >> 3) & 63;
    int ks = (idx >> 9) & 3;
    int ct = idx >> 11;
    int k = ks * 32 + ((l >> 4) << 3) + j;
    int c = ct * 16 + (l & 15);
    Wp[idx] = f2b(W[(size_t)k * D + c]);
}

__global__ void prep(const float* __restrict__ in, unsigned short* __restrict__ out,
                     const float* __restrict__ W1, unsigned short* __restrict__ Wp1,
                     const float* __restrict__ W2, unsigned short* __restrict__ Wp2,
                     int count8, int nbconv) {
    int b = blockIdx.x;
    if (b < nbconv) {
        int t = b * 256 + threadIdx.x;
        if (t >= count8) return;
        const float4* p = (const float4*)(in + (size_t)t * 8);
        float4 a = p[0], bb = p[1];
        bf16x8 o;
        o[0] = (short)f2b(a.x);  o[1] = (short)f2b(a.y);
        o[2] = (short)f2b(a.z);  o[3] = (short)f2b(a.w);
        o[4] = (short)f2b(bb.x); o[5] = (short)f2b(bb.y);
        o[6] = (short)f2b(bb.z); o[7] = (short)f2b(bb.w);
        *(bf16x8*)(out + (size_t)t * 8) = o;
    } else if (b < nbconv + 64) {
        pack_body(W1, Wp1, (b - nbconv) * 256 + threadIdx.x);
    } else {
        pack_body(W2, Wp2, (b - nbconv - 64) * 256 + threadIdx.x);
    }
}

// ---------------- MFMA GEMM: h16 = bf16(x @ W), fused as_/ad_ dots ----------------
__global__ __launch_bounds__(256) void gemm_mfma(const unsigned short* __restrict__ xb,
                                                 const unsigned short* __restrict__ Wp,
                                                 const float* __restrict__ a_src,
                                                 const float* __restrict__ a_dst,
                                                 unsigned short* __restrict__ h16,
                                                 float* __restrict__ as_, float* __restrict__ ad_,
                                                 int n) {
    __shared__ float lds[4][16][132];
    int wv = threadIdx.x >> 6;
    int lane = threadIdx.x & 63;
    int base = blockIdx.x * 64 + wv * 16;
    int arow = base + (lane & 15);
    if (arow >= n) arow = n - 1;
    const bf16x8* aptr = (const bf16x8*)(xb + (size_t)arow * D + ((lane >> 4) << 3));
    const bf16x8* bp = (const bf16x8*)Wp;

    f32x4 acc[8];
#pragma unroll
    for (int ct = 0; ct < 8; ++ct) acc[ct] = (f32x4){0.f, 0.f, 0.f, 0.f};

#pragma unroll
    for (int ks = 0; ks < 4; ++ks) {
        bf16x8 af = aptr[ks * 4];
#pragma unroll
        for (int ct = 0; ct < 8; ++ct) {
            bf16x8 bf_ = bp[(ct * 4 + ks) * 64 + lane];
            acc[ct] = __builtin_amdgcn_mfma_f32_16x16x32_bf16(af, bf_, acc[ct], 0, 0, 0);
        }
    }

    int r0 = (lane >> 4) * 4;
    int c0 = lane & 15;
#pragma unroll
    for (int ct = 0; ct < 8; ++ct)
#pragma unroll
        for (int i = 0; i < 4; ++i)
            lds[wv][r0 + i][ct * 16 + c0] = acc[ct][i];
    __syncthreads();

#pragma unroll
    for (int i = 0; i < 4; ++i) {
        int r = (lane >> 4) + i * 4;
        int gr = base + r;
        if (gr < n) {
            const float* row = lds[wv][r];
            bf16x8 o;
#pragma unroll
            for (int j = 0; j < 8; ++j) o[j] = (short)f2b(row[c0 * 8 + j]);
            *(bf16x8*)(h16 + (size_t)gr * D + c0 * 8) = o;
        }
    }

    int r = lane >> 2, q = lane & 3;
    float s1 = 0.f, s2 = 0.f;
    const float* row = lds[wv][r];
#pragma unroll
    for (int c = 0; c < 32; ++c) {
        float hv = row[q * 32 + c];
        s1 = fmaf(hv, a_src[q * 32 + c], s1);
        s2 = fmaf(hv, a_dst[q * 32 + c], s2);
    }
    s1 += __shfl_xor(s1, 1); s1 += __shfl_xor(s1, 2);
    s2 += __shfl_xor(s2, 1); s2 += __shfl_xor(s2, 2);
    int gr = base + r;
    if (q == 0 && gr < n) { as_[gr] = s1; ad_[gr] = s2; }
}

// ---------------- CSR build (graph is layer-invariant) ----------------

__global__ void deg_hist(const int* __restrict__ ad_idx, int E, int n, int* __restrict__ cnt) {
    int e = blockIdx.x * blockDim.x + threadIdx.x;
    if (e >= E + n) return;
    int dst = (e < E) ? ad_idx[E + e] : (e - E);
    atomicAdd(&cnt[dst], 1);
}

__global__ void scan1(const int* __restrict__ cnt, int* __restrict__ start,
                      int* __restrict__ bsum, int n) {
    __shared__ int lds[256];
    int t = threadIdx.x;
    int i = blockIdx.x * 256 + t;
    int v = (i < n) ? cnt[i] : 0;
    lds[t] = v;
    __syncthreads();
    for (int off = 1; off < 256; off <<= 1) {
        int o = (t >= off) ? lds[t - off] : 0;
        __syncthreads();
        lds[t] += o;
        __syncthreads();
    }
    int incl = lds[t];
    if (i < n) start[i] = incl - v;
    if (t == 255) bsum[blockIdx.x] = incl;
}

__global__ void scan2(int* __restrict__ bsum, int nb) {
    __shared__ int lds[256];
    int t = threadIdx.x;
    int v = (t < nb) ? bsum[t] : 0;
    lds[t] = v;
    __syncthreads();
    for (int off = 1; off < 256; off <<= 1) {
        int o = (t >= off) ? lds[t - off] : 0;
        __syncthreads();
        lds[t] += o;
        __syncthreads();
    }
    if (t < nb) bsum[t] = lds[t] - v;
}

__global__ void scan3(int* __restrict__ start, const int* __restrict__ bsum, int n) {
    int i = blockIdx.x * blockDim.x + threadIdx.x;
    if (i < n) start[i] += bsum[blockIdx.x];
}

__global__ void csr_scatter(const int* __restrict__ ad_idx, int E, int n,
                            const int* __restrict__ start, int* __restrict__ cursor,
                            int* __restrict__ csr_src) {
    int e = blockIdx.x * blockDim.x + threadIdx.x;
    if (e >= E + n) return;
    int src, dst;
    if (e < E) { src = ad_idx[e]; dst = ad_idx[E + e]; }
    else       { src = dst = e - E; }
    int r = atomicAdd(&cursor[dst], 1);
    csr_src[start[dst] + r] = src;
}

// ------- fused per-node edge softmax + gather + bias + relu (+ L2 head-li fusion) -------
// one wave per node. Inner gather keeps the R4-proven pattern (uniform readlane, full-wave
// 256B row reads) but batched x4 for memory-level parallelism. deg<=64 fast path.
__global__ void gat_aggregate(const int* __restrict__ csr_src, const int* __restrict__ start,
                              const int* __restrict__ deg, const float* __restrict__ as_,
                              const float* __restrict__ ad_, const unsigned short* __restrict__ h16,
                              const float* __restrict__ bias,
                              unsigned short* __restrict__ out16,                   // L1 path
                              float* __restrict__ xout, float* __restrict__ sout,   // L2 path
                              const float* __restrict__ w_lin, const float* __restrict__ b_lin,
                              const int* __restrict__ resmask, float* __restrict__ pr,
                              const int* __restrict__ num_res, int n) {
    int wid = threadIdx.x >> 6;
    int lane = threadIdx.x & 63;
    int node = blockIdx.x * 4 + wid;
    if (node >= n) return;
    int s0 = start[node];
    int dg = deg[node];
    float adv = ad_[node];

    float acc0 = 0.f, acc1 = 0.f;

    if (dg <= 64) {
        // ---- fast path: whole edge list in one register per lane ----
        bool ok = lane < dg;
        int sj = ok ? csr_src[s0 + lane] : 0;
        float v = -3.4e38f;
        if (ok) {
            v = as_[sj] + adv;
            v = v >= 0.f ? v : 0.2f * v;
        }
        float m = v;
        for (int off = 32; off; off >>= 1) m = fmaxf(m, __shfl_xor(m, off));
        float e = ok ? __expf(v - m) : 0.f;
        float ds = e;
        for (int off = 32; off; off >>= 1) ds += __shfl_xor(ds, off);
        float inv = 1.f / (ds + 1e-16f);

        int mc4 = (dg + 3) & ~3;          // masked lanes carry e=0, sj=0 -> no tail logic
        for (int l = 0; l < mc4; l += 4) {
            float a0 = __shfl(e, l),     a1 = __shfl(e, l + 1);
            float a2 = __shfl(e, l + 2), a3 = __shfl(e, l + 3);
            int   t0 = __shfl(sj, l),     t1 = __shfl(sj, l + 1);
            int   t2 = __shfl(sj, l + 2), t3 = __shfl(sj, l + 3);
            unsigned h0 = *(const unsigned*)(h16 + (size_t)t0 * D + lane * 2);
            unsigned h1 = *(const unsigned*)(h16 + (size_t)t1 * D + lane * 2);
            unsigned h2 = *(const unsigned*)(h16 + (size_t)t2 * D + lane * 2);
            unsigned h3 = *(const unsigned*)(h16 + (size_t)t3 * D + lane * 2);
            acc0 = fmaf(a0, __uint_as_float(h0 << 16), acc0);
            acc1 = fmaf(a0, __uint_as_float(h0 & 0xffff0000u), acc1);
            acc0 = fmaf(a1, __uint_as_float(h1 << 16), acc0);
            acc1 = fmaf(a1, __uint_as_float(h1 & 0xffff0000u), acc1);
            acc0 = fmaf(a2, __uint_as_float(h2 << 16), acc0);
            acc1 = fmaf(a2, __uint_as_float(h2 & 0xffff0000u), acc1);
            acc0 = fmaf(a3, __uint_as_float(h3 << 16), acc0);
            acc1 = fmaf(a3, __uint_as_float(h3 & 0xffff0000u), acc1);
        }
        acc0 *= inv;                       // alpha normalization hoisted out of the loop
        acc1 *= inv;
    } else {
        // ---- fallback (deg > 64): R4/R6 CACHE path ----
        float vreg[CACHE];
        int   sreg[CACHE];
        float m = -3.4e38f;
#pragma unroll
        for (int c = 0; c < CACHE; ++c) {
            int j = c * 64 + lane;
            bool ok = j < dg;
            int s = ok ? csr_src[s0 + j] : 0;
            sreg[c] = s;
            float v = -3.4e38f;
            if (ok) {
                v = as_[s] + adv;
                v = v >= 0.f ? v : 0.2f * v;
            }
            vreg[c] = v;
            m = fmaxf(m, v);
        }
        for (int off = 32; off; off >>= 1) m = fmaxf(m, __shfl_xor(m, off));
        float dsum = 0.f;
#pragma unroll
        for (int c = 0; c < CACHE; ++c) {
            int j = c * 64 + lane;
            float e = (j < dg) ? __expf(vreg[c] - m) : 0.f;
            vreg[c] = e;
            dsum += e;
        }
        for (int off = 32; off; off >>= 1) dsum += __shfl_xor(dsum, off);
        float inv = 1.f / (dsum + 1e-16f);
#pragma unroll
        for (int c = 0; c < CACHE; ++c) {
            if (c * 64 < dg) {
                int mc = min(64, dg - c * 64);
                for (int l = 0; l < mc; ++l) {
                    float a   = __shfl(vreg[c], l) * inv;
                    int  srcj = __shfl(sreg[c], l);
                    unsigned hv = *(const unsigned*)(h16 + (size_t)srcj * D + lane * 2);
                    acc0 = fmaf(a, __uint_as_float(hv << 16), acc0);
                    acc1 = fmaf(a, __uint_as_float(hv & 0xffff0000u), acc1);
                }
            }
        }
    }

    float2 bv = *(const float2*)(bias + lane * 2);
    float o0 = acc0 + bv.x, o1 = acc1 + bv.y;
    o0 = o0 > 0.f ? o0 : 0.f;
    o1 = o1 > 0.f ? o1 : 0.f;

    if (out16) {                                   // layer 1: bf16 for next GEMM
        ushort2 u2;
        u2.x = f2b(o0);
        u2.y = f2b(o1);
        *(ushort2*)(out16 + (size_t)node * D + lane * 2) = u2;
    } else {                                       // layer 2: d_out writes + fused head li
        *(float2*)(xout + (size_t)node * D + lane * 2) = make_float2(o0, o1);
        if (node < num_res[0])
            *(float2*)(sout + (size_t)node * D + lane * 2) = make_float2(o0, o1);
        float2 wv = *(const float2*)(w_lin + lane * 2);
        float part = fmaf(o0, wv.x, o1 * wv.y);
        for (int off = 32; off; off >>= 1) part += __shfl_xor(part, off);
        if (lane == 0) {
            float s = part + b_lin[0];
            if (resmask[node] == 0) s = -1000000000.0f;
            pr[node] = s;
        }
    }
}

// ---------------- head ----------------

__global__ void head_max(const float* __restrict__ pr, unsigned* __restrict__ limax_u, int n) {
    unsigned mx = 0u;
    for (int i = blockIdx.x * blockDim.x + threadIdx.x; i < n; i += gridDim.x * blockDim.x) {
        unsigned e = fenc(pr[i]);
        mx = mx > e ? mx : e;
    }
    for (int off = 32; off; off >>= 1) {
        unsigned o = __shfl_xor(mx, off);
        mx = mx > o ? mx : o;
    }
    if ((threadIdx.x & 63) == 0) atomicMax(limax_u, mx);
}

__global__ void head_exp(float* __restrict__ pr, const unsigned* __restrict__ limax_u,
                         float* __restrict__ sumexp, const int* __restrict__ resmask,
                         float* __restrict__ maskf, int n) {
    int i = blockIdx.x * blockDim.x + threadIdx.x;
    float m = fdec(*limax_u);
    float u = 0.f;
    if (i < n) {
        u = expf(pr[i] - m);
        pr[i] = u;
        maskf[i] = (float)resmask[i];
    }
    float t = u;
    for (int off = 32; off; off >>= 1) t += __shfl_down(t, off);
    if ((threadIdx.x & 63) == 0) atomicAdd(sumexp, t);
}

__global__ void head_final(float* __restrict__ pr, const float* __restrict__ sumexp,
                           const float* __restrict__ res, float* __restrict__ loss_out, int n) {
    int i = blockIdx.x * blockDim.x + threadIdx.x;
    float lt = 0.f;
    if (i < n) {
        float p = pr[i] / (*sumexp);
        pr[i] = p;
        float pc = fminf(fmaxf(p, 1e-10f), 1.0f);
        lt = -logf(pc) * res[i];
    }
    float t = lt;
    for (int off = 32; off; off >>= 1) t += __shfl_down(t, off);
    if ((threadIdx.x & 63) == 0) atomicAdd(loss_out, t);
}

extern "C" void kernel_launch(void* const* d_in, const int* in_sizes, int n_in,
                              void* d_out, int out_size, void* d_ws, size_t ws_size,
                              hipStream_t stream) {
    const float* input_node = (const float*)d_in[0];
    const int*   inputad    = (const int*)d_in[1];
    const float* res        = (const float*)d_in[2];
    const int*   resmask    = (const int*)d_in[3];
    const int*   num_res    = (const int*)d_in[4];
    const float* W1     = (const float*)d_in[5];
    const float* a_src1 = (const float*)d_in[6];
    const float* a_dst1 = (const float*)d_in[7];
    const float* b1     = (const float*)d_in[8];
    const float* W2     = (const float*)d_in[9];
    const float* a_src2 = (const float*)d_in[10];
    const float* a_dst2 = (const float*)d_in[11];
    const float* b2     = (const float*)d_in[12];
    const float* w_lin  = (const float*)d_in[13];
    const float* b_lin  = (const float*)d_in[14];

    int n = in_sizes[0] / D;
    int E = in_sizes[1] / 2;
    int Et = E + n;

    // workspace carve (16B aligned pieces)
    char* w = (char*)d_ws;
    unsigned short* xb16 = (unsigned short*)w; w += (size_t)n * D * 2;
    unsigned short* h16  = (unsigned short*)w; w += (size_t)n * D * 2;
    unsigned short* Wp1 = (unsigned short*)w; w += 16384 * 2;
    unsigned short* Wp2 = (unsigned short*)w; w += 16384 * 2;
    float* as_   = (float*)w; w += (size_t)n * 4;
    float* ad_   = (float*)w; w += (size_t)n * 4;
    int*   deg   = (int*)w;   w += (size_t)n * 4;
    int*   startv= (int*)w;   w += (size_t)n * 4;
    int*   cursor= (int*)w;   w += (size_t)n * 4;
    int*   csr_src=(int*)w;   w += (size_t)Et * 4;
    int*   bsum  = (int*)w;   w += 1024;
    unsigned* limax_u = (unsigned*)w; w += 16;
    float* sumexp = (float*)w; w += 16;

    // d_out carve
    float* out0  = (float*)d_out;            // loss (1)
    float* prob  = out0 + 1;                 // N
    float* xout  = prob + n;                 // N*D
    float* maskf = xout + (size_t)n * D;     // N
    float* sout  = maskf + n;                // K*D

    dim3 blk(256);
    auto cdiv = [](long long a, long long b) { return (unsigned)((a + b - 1) / b); };
    unsigned nb = cdiv(n, 256);

    // scalar zero-inits up front
    hipMemsetAsync(limax_u, 0, 4, stream);
    hipMemsetAsync(sumexp, 0, 4, stream);
    hipMemsetAsync(out0, 0, 4, stream);
    hipMemsetAsync(deg, 0, (size_t)n * 4, stream);
    hipMemsetAsync(cursor, 0, (size_t)n * 4, stream);

    // ---- conversions / packing (fused) ----
    int count8 = n * D / 8;
    unsigned nbconv = cdiv(count8, 256);
    prep<<<nbconv + 128, blk, 0, stream>>>(input_node, xb16, W1, Wp1, W2, Wp2, count8, (int)nbconv);

    // ---- CSR build (once; graph shared by both layers) ----
    deg_hist<<<cdiv(Et, 256), blk, 0, stream>>>(inputad, E, n, deg);
    scan1<<<nb, blk, 0, stream>>>(deg, startv, bsum, n);
    scan2<<<1, blk, 0, stream>>>(bsum, (int)nb);
    scan3<<<nb, blk, 0, stream>>>(startv, bsum, n);
    csr_scatter<<<cdiv(Et, 256), blk, 0, stream>>>(inputad, E, n, startv, cursor, csr_src);

    unsigned agg_grid = cdiv(n, 4);
    unsigned gemm_grid = cdiv(n, 64);

    // ---- Layer 1 ----
    gemm_mfma<<<gemm_grid, blk, 0, stream>>>(xb16, Wp1, a_src1, a_dst1, h16, as_, ad_, n);
    gat_aggregate<<<agg_grid, blk, 0, stream>>>(csr_src, startv, deg, as_, ad_, h16, b1,
                                                xb16, nullptr, nullptr, nullptr, nullptr,
                                                nullptr, nullptr, nullptr, n);

    // ---- Layer 2 (writes straight into d_out; fused head li) ----
    gemm_mfma<<<gemm_grid, blk, 0, stream>>>(xb16, Wp2, a_src2, a_dst2, h16, as_, ad_, n);
    gat_aggregate<<<agg_grid, blk, 0, stream>>>(csr_src, startv, deg, as_, ad_, h16, b2,
                                                nullptr, xout, sout, w_lin, b_lin,
                                                resmask, prob, num_res, n);

    // ---- Head ----
    head_max<<<196, blk, 0, stream>>>(prob, limax_u, n);
    head_exp<<<nb, blk, 0, stream>>>(prob, limax_u, sumexp, resmask, maskf, n);
    head_final<<<nb, blk, 0, stream>>>(prob, sumexp, res, out0, n);
}